// Round 22
// baseline (43.619 us; speedup 1.0000x reference)
//
#include <hip/hip_runtime.h>

// ChamferDistance  B=16, N=M=4096, D=3, fp32 in/out (scalar out).
// R18/R21 cd_main (best, reproduced 37.1us) + R22: tail merged into ONE
// kernel via deterministic int64 fixed-point atomicAdd + ticket-counter
// finish (integer add is associative -> bit-stable across graph replays).
#define BQ     16
#define NPTS   4096
#define TOTAL  (BQ * NPTS)              // 65536 points per side
#define NCMB   128                      // combine blocks
#define FIXSCALE 16777216.0             // 2^24

// ws layout: rowmin[8][TOTAL] floats (2 MiB), then {int64 acc, u32 counter}.
#define ROWMIN_FLOATS ((size_t)8 * TOTAL)
#define ACC_OFF       (ROWMIN_FLOATS * 4)
#define WS_NEED       (ACC_OFF + 16)

typedef __attribute__((ext_vector_type(8)))  short short8;
typedef __attribute__((ext_vector_type(16))) float f32x16;

__device__ __forceinline__ unsigned short f2bf(float x) {
    union { float f; unsigned u; } v; v.f = x;
    unsigned r = v.u + 0x7FFFu + ((v.u >> 16) & 1u);    // RNE
    return (unsigned short)(r >> 16);
}
__device__ __forceinline__ float bf2f(unsigned short h) {
    union { float f; unsigned u; } v; v.u = ((unsigned)h) << 16; return v.f;
}
#define BF_ONE 0x3F80

// Min-reduce over each 32-lane half: 4 DPP stages (VALU) + 1 ds_swizzle xor16.
__device__ __forceinline__ float min32_dpp(float v) {
    int t;
    t = __builtin_amdgcn_update_dpp(__float_as_int(v), __float_as_int(v),
                                    0x0B1, 0xf, 0xf, true);   // quad [1,0,3,2]
    v = fminf(v, __int_as_float(t));
    t = __builtin_amdgcn_update_dpp(__float_as_int(v), __float_as_int(v),
                                    0x04E, 0xf, 0xf, true);   // quad [2,3,0,1]
    v = fminf(v, __int_as_float(t));
    t = __builtin_amdgcn_update_dpp(__float_as_int(v), __float_as_int(v),
                                    0x141, 0xf, 0xf, true);   // row_half_mirror
    v = fminf(v, __int_as_float(t));
    t = __builtin_amdgcn_update_dpp(__float_as_int(v), __float_as_int(v),
                                    0x140, 0xf, 0xf, true);   // row_mirror
    v = fminf(v, __int_as_float(t));
    t = __builtin_amdgcn_ds_swizzle(__float_as_int(v), 0x401F); // xor16 in 32
    v = fminf(v, __int_as_float(t));
    return v;
}

// ---- R5/R7-verified 32x32x16 slot maps (absmax=0) ----
__device__ __forceinline__ uint4 make_bslots(const float* __restrict__ pts,
                                             int tile, int lane) {
    const int pidx = lane & 31, g = lane >> 5;
    const float* pp = pts + (size_t)(tile * 32 + pidx) * 3;
    const float x = pp[0], y = pp[1], z = pp[2];
    const unsigned short xh = f2bf(x), yh = f2bf(y), zh = f2bf(z);
    const unsigned short xl = f2bf(x - bf2f(xh)), yl = f2bf(y - bf2f(yh)),
                         zl = f2bf(z - bf2f(zh));
    const unsigned short m2xh = f2bf(-2.0f * bf2f(xh)), m2yh = f2bf(-2.0f * bf2f(yh)),
                         m2zh = f2bf(-2.0f * bf2f(zh));
    const unsigned short m2xl = f2bf(-2.0f * bf2f(xl)), m2yl = f2bf(-2.0f * bf2f(yl)),
                         m2zl = f2bf(-2.0f * bf2f(zl));
    const float s2 = fmaf(x, x, fmaf(y, y, z * z));
    const unsigned short s2h = f2bf(s2);
    const unsigned short s2l = f2bf(s2 - bf2f(s2h));
    unsigned short s[8];
    if (g == 0) { s[0]=m2xh; s[1]=m2yh; s[2]=m2zh; s[3]=m2xl; s[4]=m2yl; s[5]=m2zl; s[6]=m2xh; s[7]=m2yh; }
    else        { s[0]=m2zh; s[1]=BF_ONE; s[2]=BF_ONE; s[3]=s2h; s[4]=s2l; s[5]=0; s[6]=0; s[7]=0; }
    uint4 o;
    o.x = (unsigned)s[0] | ((unsigned)s[1] << 16);
    o.y = (unsigned)s[2] | ((unsigned)s[3] << 16);
    o.z = (unsigned)s[4] | ((unsigned)s[5] << 16);
    o.w = (unsigned)s[6] | ((unsigned)s[7] << 16);
    return o;
}

__device__ __forceinline__ short8 make_aslots(const float* __restrict__ pts,
                                              int point, int g) {
    const float* pp = pts + (size_t)point * 3;
    const float x = pp[0], y = pp[1], z = pp[2];
    const unsigned short xh = f2bf(x), yh = f2bf(y), zh = f2bf(z);
    const unsigned short xl = f2bf(x - bf2f(xh)), yl = f2bf(y - bf2f(yh)),
                         zl = f2bf(z - bf2f(zh));
    const float s2 = fmaf(x, x, fmaf(y, y, z * z));
    const unsigned short s2h = f2bf(s2);
    const unsigned short s2l = f2bf(s2 - bf2f(s2h));
    unsigned short s[8];
    if (g == 0) { s[0]=xh; s[1]=yh; s[2]=zh; s[3]=xh; s[4]=yh; s[5]=zh; s[6]=xl; s[7]=yl; }
    else        { s[0]=zl; s[1]=s2h; s[2]=s2l; s[3]=BF_ONE; s[4]=BF_ONE; s[5]=0; s[6]=0; s[7]=0; }
    union { unsigned u[4]; short8 v; } o;
    o.u[0] = (unsigned)s[0] | ((unsigned)s[1] << 16);
    o.u[1] = (unsigned)s[2] | ((unsigned)s[3] << 16);
    o.u[2] = (unsigned)s[4] | ((unsigned)s[5] << 16);
    o.u[3] = (unsigned)s[6] | ((unsigned)s[7] << 16);
    return o.v;
}

// Main kernel (identical to R18/R21 best).
__global__ __launch_bounds__(256, 4) void cd_main(
        const float* __restrict__ p1, const float* __restrict__ p2,
        float* __restrict__ rowmin) {
    const int dir  = blockIdx.y;
    const float* __restrict__ A  = dir ? p2 : p1;
    const float* __restrict__ Bp = dir ? p1 : p2;

    const int bx   = blockIdx.x;
    const int b    = bx >> 6;                         // batch
    const int rg   = (bx >> 2) & 15;                  // rowgroup (256 rows)
    const int cg   = bx & 3;                          // colgroup (32 tiles)
    const int wave = threadIdx.x >> 6;
    const int lane = threadIdx.x & 63;
    const int pidx = lane & 31, g = lane >> 5;

    __shared__ uint4 spanel[32 * 64];                 // 32 KB

    const float* __restrict__ Bbase = Bp + (size_t)(b * NPTS + cg * 1024) * 3;
#pragma unroll
    for (int k = 0; k < 8; ++k) {
        const int s = threadIdx.x + k * 256;          // 2048 slots
        spanel[s] = make_bslots(Bbase, s >> 6, s & 63);
    }

    const int rowbase = b * NPTS + rg * 256 + wave * 64;

    const short8 a0 = make_aslots(A, rowbase      + pidx, g);
    const short8 a1 = make_aslots(A, rowbase + 32 + pidx, g);

    f32x16 zero, r0, r1;
#pragma unroll
    for (int e = 0; e < 16; ++e) { zero[e] = 0.0f; r0[e] = 3.0e38f; r1[e] = 3.0e38f; }

    __syncthreads();                                  // panel ready

#define CD_COMPUTE(C0, C1)                                                    \
    do {                                                                      \
        const short8 bf0 = *reinterpret_cast<const short8*>(&(C0));           \
        const short8 bf1 = *reinterpret_cast<const short8*>(&(C1));           \
        f32x16 d0, d1;                                                        \
        d0 = __builtin_amdgcn_mfma_f32_32x32x16_bf16(a0, bf0, zero, 0, 0, 0); \
        d1 = __builtin_amdgcn_mfma_f32_32x32x16_bf16(a0, bf1, zero, 0, 0, 0); \
        _Pragma("unroll") for (int e = 0; e < 16; ++e)                        \
            r0[e] = fminf(r0[e], fminf(d0[e], d1[e]));                        \
        d0 = __builtin_amdgcn_mfma_f32_32x32x16_bf16(a1, bf0, zero, 0, 0, 0); \
        d1 = __builtin_amdgcn_mfma_f32_32x32x16_bf16(a1, bf1, zero, 0, 0, 0); \
        _Pragma("unroll") for (int e = 0; e < 16; ++e)                        \
            r1[e] = fminf(r1[e], fminf(d0[e], d1[e]));                        \
    } while (0)

    int t0 = wave * 8;
    uint4 c0 = spanel[t0 * 64 + lane], c1 = spanel[(t0 + 1) * 64 + lane];
#pragma unroll 1
    for (int i = 0; i < 15; ++i) {
        const int tn = (t0 + 2) & 31;
        uint4 n0 = spanel[tn * 64 + lane];
        uint4 n1 = spanel[(tn + 1) * 64 + lane];
        CD_COMPUTE(c0, c1);
        c0 = n0; c1 = n1; t0 = tn;
    }
    CD_COMPUTE(c0, c1);
#undef CD_COMPUTE

    float* __restrict__ outr = rowmin + (size_t)(dir * 4 + cg) * TOTAL;
#pragma unroll
    for (int e = 0; e < 16; ++e) {
        const float v0 = min32_dpp(r0[e]);
        const float v1 = min32_dpp(r1[e]);
        const int rl = (e & 3) + 8 * (e >> 2) + 4 * g;
        if (pidx == 0) {
            outr[rowbase +      rl] = fmaxf(v0, 0.0f);
            outr[rowbase + 32 + rl] = fmaxf(v1, 0.0f);
        }
    }
}

// Fused combine+final: per-block partial -> int64 fixed-point atomicAdd
// (associative -> deterministic) -> last block (ticket) writes out.
__global__ __launch_bounds__(256) void cd_combine(const float* __restrict__ rowmin,
                                                  unsigned long long* __restrict__ acc,
                                                  unsigned* __restrict__ counter,
                                                  float* __restrict__ out) {
    __shared__ float sred[256];
    const int tid = blockIdx.x * 256 + threadIdx.x;   // [0, 32768)
    float s = 0.0f;
#pragma unroll
    for (int k = 0; k < 4; ++k) {
        const int i   = tid + k * 32768;              // [0, 131072)
        const int d   = i >> 16;                      // dir
        const int row = i & (TOTAL - 1);
        const float* base = rowmin + (size_t)d * 4 * TOTAL + row;
        s += fminf(fminf(base[0], base[TOTAL]),
                   fminf(base[2 * TOTAL], base[3 * TOTAL]));
    }
    sred[threadIdx.x] = s;
    __syncthreads();
    for (int st = 128; st > 0; st >>= 1) {
        if (threadIdx.x < st) sred[threadIdx.x] += sred[threadIdx.x + st];
        __syncthreads();
    }
    if (threadIdx.x == 0) {
        const unsigned long long ip =
            (unsigned long long)(double)((double)sred[0] * FIXSCALE);
        atomicAdd(acc, ip);
        __threadfence();
        const unsigned done = atomicAdd(counter, 1u);
        if (done == NCMB - 1) {
            const unsigned long long total = atomicAdd(acc, 0ull);
            out[0] = (float)((double)total / FIXSCALE / (double)BQ);
        }
    }
}

// ---------------- fallback (ws too small): R2 LDS-scalar path ----------------
__global__ __launch_bounds__(256) void cd_init_ws(unsigned int* __restrict__ ws) {
    ws[blockIdx.x * 256 + threadIdx.x] = 0x7F800000u;
}
#define F_APT 8
__global__ __launch_bounds__(256) void cd_min_lds(
        const float* __restrict__ p1, const float* __restrict__ p2,
        unsigned int* __restrict__ wsmin) {
    const int dir = blockIdx.y;
    const float* __restrict__ Aset = dir ? p2 : p1;
    const float* __restrict__ Bset = dir ? p1 : p2;
    unsigned int* __restrict__ outmin = wsmin + dir * TOTAL;
    const int atile = blockIdx.x / 16;
    const int mtile = blockIdx.x % 16;
    const int a0 = atile * 2048;
    const int m0 = (a0 / NPTS) * NPTS + mtile * 256;
    __shared__ float4 sbf[256];
    {
        const float* bpn = Bset + (size_t)(m0 + threadIdx.x) * 3;
        float bx = bpn[0], by = bpn[1], bz = bpn[2];
        sbf[threadIdx.x] = make_float4(-2.0f*bx, -2.0f*by, -2.0f*bz,
                                       fmaf(bx,bx,fmaf(by,by,bz*bz)));
    }
    __syncthreads();
    float ax[F_APT], ay[F_APT], az_[F_APT], q2[F_APT], mn[F_APT];
#pragma unroll
    for (int k = 0; k < F_APT; ++k) {
        const int ai = a0 + k*256 + threadIdx.x;
        const float* ap = Aset + (size_t)ai * 3;
        ax[k]=ap[0]; ay[k]=ap[1]; az_[k]=ap[2];
        q2[k]=fmaf(ax[k],ax[k],fmaf(ay[k],ay[k],az_[k]*az_[k]));
        mn[k]=3.0e38f;
    }
#pragma unroll 2
    for (int j = 0; j < 256; j += 2) {
        const float4 b0 = sbf[j], b1 = sbf[j+1];
#pragma unroll
        for (int k = 0; k < F_APT; ++k) {
            float d0 = fmaf(az_[k],b0.z,b0.w); d0=fmaf(ay[k],b0.y,d0); d0=fmaf(ax[k],b0.x,d0);
            float d1 = fmaf(az_[k],b1.z,b1.w); d1=fmaf(ay[k],b1.y,d1); d1=fmaf(ax[k],b1.x,d1);
            mn[k] = fminf(fminf(mn[k], d0), d1);
        }
    }
#pragma unroll
    for (int k = 0; k < F_APT; ++k) {
        const int ai = a0 + k*256 + threadIdx.x;
        atomicMin(&outmin[ai], __float_as_uint(fmaxf(q2[k]+mn[k], 0.0f)));
    }
}
__global__ __launch_bounds__(1024) void cd_reduce_single(const float* __restrict__ wsmin,
                                                         float* __restrict__ out) {
    __shared__ float sred[1024];
    const float4* __restrict__ v = (const float4*)wsmin;
    float s = 0.0f;
    for (int i = threadIdx.x; i < (2*TOTAL)/4; i += 1024) {
        float4 x = v[i]; s += (x.x + x.y) + (x.z + x.w);
    }
    sred[threadIdx.x] = s;
    __syncthreads();
    for (int st = 512; st > 0; st >>= 1) {
        if (threadIdx.x < st) sred[threadIdx.x] += sred[threadIdx.x + st];
        __syncthreads();
    }
    if (threadIdx.x == 0) out[0] = sred[0] * (1.0f / (float)BQ);
}

extern "C" void kernel_launch(void* const* d_in, const int* in_sizes, int n_in,
                              void* d_out, int out_size, void* d_ws, size_t ws_size,
                              hipStream_t stream) {
    const float* p1 = (const float*)d_in[0];
    const float* p2 = (const float*)d_in[1];
    float* out = (float*)d_out;

    if (ws_size >= WS_NEED) {
        float* rowmin = (float*)d_ws;                       // 2 MiB
        unsigned long long* acc = (unsigned long long*)((char*)d_ws + ACC_OFF);
        unsigned* counter = (unsigned*)((char*)d_ws + ACC_OFF + 8);

        hipMemsetAsync((void*)acc, 0, 16, stream);          // acc + counter
        dim3 grid(1024, 2, 1);
        cd_main<<<grid, 256, 0, stream>>>(p1, p2, rowmin);
        cd_combine<<<NCMB, 256, 0, stream>>>(rowmin, acc, counter, out);
    } else {
        unsigned* wsmin = (unsigned*)d_ws;                  // 512 KiB
        cd_init_ws<<<(2 * TOTAL) / 256, 256, 0, stream>>>(wsmin);
        dim3 grid(512, 2, 1);
        cd_min_lds<<<grid, 256, 0, stream>>>(p1, p2, wsmin);
        cd_reduce_single<<<1, 1024, 0, stream>>>((const float*)wsmin, out);
    }
}

// Round 23
// 36.998 us; speedup vs baseline: 1.1790x; 1.1790x over previous
//
#include <hip/hip_runtime.h>

// ChamferDistance  B=16, N=M=4096, D=3, fp32 in/out (scalar out).
// FINAL = R18/R21 config (best, 37.1us, reproduced): 32x32x16-bf16 MFMA,
// per-block LDS panel, DPP epilogue, two-stage deterministic tail.
// Closed levers: MFMA shape (equal), occupancy (4 waves/SIMD only; ~124-reg
// unified live set spills at 6/8), AGPR pinning (no effect), frag hoisting
// (neutral), depth-2 prefetch (spills), tail fusion (regressed).
#define BQ     16
#define NPTS   4096
#define TOTAL  (BQ * NPTS)              // 65536 points per side
#define NPART  128

// ws layout: rowmin[8][TOTAL] floats (2 dirs x 4 colgroups), then partials.
#define ROWMIN_FLOATS ((size_t)8 * TOTAL)
#define WS_NEED (ROWMIN_FLOATS * 4 + (size_t)NPART * 4)

typedef __attribute__((ext_vector_type(8)))  short short8;
typedef __attribute__((ext_vector_type(16))) float f32x16;

__device__ __forceinline__ unsigned short f2bf(float x) {
    union { float f; unsigned u; } v; v.f = x;
    unsigned r = v.u + 0x7FFFu + ((v.u >> 16) & 1u);    // RNE
    return (unsigned short)(r >> 16);
}
__device__ __forceinline__ float bf2f(unsigned short h) {
    union { float f; unsigned u; } v; v.u = ((unsigned)h) << 16; return v.f;
}
#define BF_ONE 0x3F80

// Min-reduce over each 32-lane half: 4 DPP stages (VALU) + 1 ds_swizzle xor16.
__device__ __forceinline__ float min32_dpp(float v) {
    int t;
    t = __builtin_amdgcn_update_dpp(__float_as_int(v), __float_as_int(v),
                                    0x0B1, 0xf, 0xf, true);   // quad [1,0,3,2]
    v = fminf(v, __int_as_float(t));
    t = __builtin_amdgcn_update_dpp(__float_as_int(v), __float_as_int(v),
                                    0x04E, 0xf, 0xf, true);   // quad [2,3,0,1]
    v = fminf(v, __int_as_float(t));
    t = __builtin_amdgcn_update_dpp(__float_as_int(v), __float_as_int(v),
                                    0x141, 0xf, 0xf, true);   // row_half_mirror
    v = fminf(v, __int_as_float(t));
    t = __builtin_amdgcn_update_dpp(__float_as_int(v), __float_as_int(v),
                                    0x140, 0xf, 0xf, true);   // row_mirror
    v = fminf(v, __int_as_float(t));
    t = __builtin_amdgcn_ds_swizzle(__float_as_int(v), 0x401F); // xor16 in 32
    v = fminf(v, __int_as_float(t));
    return v;
}

// ---- R5/R7-verified 32x32x16 slot maps (absmax=0) ----
__device__ __forceinline__ uint4 make_bslots(const float* __restrict__ pts,
                                             int tile, int lane) {
    const int pidx = lane & 31, g = lane >> 5;
    const float* pp = pts + (size_t)(tile * 32 + pidx) * 3;
    const float x = pp[0], y = pp[1], z = pp[2];
    const unsigned short xh = f2bf(x), yh = f2bf(y), zh = f2bf(z);
    const unsigned short xl = f2bf(x - bf2f(xh)), yl = f2bf(y - bf2f(yh)),
                         zl = f2bf(z - bf2f(zh));
    const unsigned short m2xh = f2bf(-2.0f * bf2f(xh)), m2yh = f2bf(-2.0f * bf2f(yh)),
                         m2zh = f2bf(-2.0f * bf2f(zh));
    const unsigned short m2xl = f2bf(-2.0f * bf2f(xl)), m2yl = f2bf(-2.0f * bf2f(yl)),
                         m2zl = f2bf(-2.0f * bf2f(zl));
    const float s2 = fmaf(x, x, fmaf(y, y, z * z));
    const unsigned short s2h = f2bf(s2);
    const unsigned short s2l = f2bf(s2 - bf2f(s2h));
    unsigned short s[8];
    if (g == 0) { s[0]=m2xh; s[1]=m2yh; s[2]=m2zh; s[3]=m2xl; s[4]=m2yl; s[5]=m2zl; s[6]=m2xh; s[7]=m2yh; }
    else        { s[0]=m2zh; s[1]=BF_ONE; s[2]=BF_ONE; s[3]=s2h; s[4]=s2l; s[5]=0; s[6]=0; s[7]=0; }
    uint4 o;
    o.x = (unsigned)s[0] | ((unsigned)s[1] << 16);
    o.y = (unsigned)s[2] | ((unsigned)s[3] << 16);
    o.z = (unsigned)s[4] | ((unsigned)s[5] << 16);
    o.w = (unsigned)s[6] | ((unsigned)s[7] << 16);
    return o;
}

__device__ __forceinline__ short8 make_aslots(const float* __restrict__ pts,
                                              int point, int g) {
    const float* pp = pts + (size_t)point * 3;
    const float x = pp[0], y = pp[1], z = pp[2];
    const unsigned short xh = f2bf(x), yh = f2bf(y), zh = f2bf(z);
    const unsigned short xl = f2bf(x - bf2f(xh)), yl = f2bf(y - bf2f(yh)),
                         zl = f2bf(z - bf2f(zh));
    const float s2 = fmaf(x, x, fmaf(y, y, z * z));
    const unsigned short s2h = f2bf(s2);
    const unsigned short s2l = f2bf(s2 - bf2f(s2h));
    unsigned short s[8];
    if (g == 0) { s[0]=xh; s[1]=yh; s[2]=zh; s[3]=xh; s[4]=yh; s[5]=zh; s[6]=xl; s[7]=yl; }
    else        { s[0]=zl; s[1]=s2h; s[2]=s2l; s[3]=BF_ONE; s[4]=BF_ONE; s[5]=0; s[6]=0; s[7]=0; }
    union { unsigned u[4]; short8 v; } o;
    o.u[0] = (unsigned)s[0] | ((unsigned)s[1] << 16);
    o.u[1] = (unsigned)s[2] | ((unsigned)s[3] << 16);
    o.u[2] = (unsigned)s[4] | ((unsigned)s[5] << 16);
    o.u[3] = (unsigned)s[6] | ((unsigned)s[7] << 16);
    return o.v;
}

// Main kernel.  Block = 4 waves (256 rows); wave = 64 rows (2 x 32-row frags).
// Block builds its colgroup's 32-tile (1024-col) B panel in LDS (32 KB), then
// each wave sweeps the 32 tiles (start offset wave*8 desyncs waves).
// grid = (16 batches * 16 rowgroups * 4 colgroups, 2 dirs) = (1024, 2).
__global__ __launch_bounds__(256, 4) void cd_main(
        const float* __restrict__ p1, const float* __restrict__ p2,
        float* __restrict__ rowmin) {
    const int dir  = blockIdx.y;
    const float* __restrict__ A  = dir ? p2 : p1;
    const float* __restrict__ Bp = dir ? p1 : p2;

    const int bx   = blockIdx.x;
    const int b    = bx >> 6;                         // batch
    const int rg   = (bx >> 2) & 15;                  // rowgroup (256 rows)
    const int cg   = bx & 3;                          // colgroup (32 tiles)
    const int wave = threadIdx.x >> 6;
    const int lane = threadIdx.x & 63;
    const int pidx = lane & 31, g = lane >> 5;

    __shared__ uint4 spanel[32 * 64];                 // 32 KB

    // Build panel from raw points (1024 col-points of this colgroup).
    const float* __restrict__ Bbase = Bp + (size_t)(b * NPTS + cg * 1024) * 3;
#pragma unroll
    for (int k = 0; k < 8; ++k) {
        const int s = threadIdx.x + k * 256;          // 2048 slots
        spanel[s] = make_bslots(Bbase, s >> 6, s & 63);
    }

    const int rowbase = b * NPTS + rg * 256 + wave * 64;

    const short8 a0 = make_aslots(A, rowbase      + pidx, g);
    const short8 a1 = make_aslots(A, rowbase + 32 + pidx, g);

    f32x16 zero, r0, r1;
#pragma unroll
    for (int e = 0; e < 16; ++e) { zero[e] = 0.0f; r0[e] = 3.0e38f; r1[e] = 3.0e38f; }

    __syncthreads();                                  // panel ready

#define CD_COMPUTE(C0, C1)                                                    \
    do {                                                                      \
        const short8 bf0 = *reinterpret_cast<const short8*>(&(C0));           \
        const short8 bf1 = *reinterpret_cast<const short8*>(&(C1));           \
        f32x16 d0, d1;                                                        \
        d0 = __builtin_amdgcn_mfma_f32_32x32x16_bf16(a0, bf0, zero, 0, 0, 0); \
        d1 = __builtin_amdgcn_mfma_f32_32x32x16_bf16(a0, bf1, zero, 0, 0, 0); \
        _Pragma("unroll") for (int e = 0; e < 16; ++e)                        \
            r0[e] = fminf(r0[e], fminf(d0[e], d1[e]));                        \
        d0 = __builtin_amdgcn_mfma_f32_32x32x16_bf16(a1, bf0, zero, 0, 0, 0); \
        d1 = __builtin_amdgcn_mfma_f32_32x32x16_bf16(a1, bf1, zero, 0, 0, 0); \
        _Pragma("unroll") for (int e = 0; e < 16; ++e)                        \
            r1[e] = fminf(r1[e], fminf(d0[e], d1[e]));                        \
    } while (0)

    // 32 tiles = 16 pairs from LDS; wave starts at tile wave*8 (desync).
    // Depth-1 register prefetch covers ds_read latency.
    int t0 = wave * 8;
    uint4 c0 = spanel[t0 * 64 + lane], c1 = spanel[(t0 + 1) * 64 + lane];
#pragma unroll 1
    for (int i = 0; i < 15; ++i) {
        const int tn = (t0 + 2) & 31;
        uint4 n0 = spanel[tn * 64 + lane];
        uint4 n1 = spanel[(tn + 1) * 64 + lane];
        CD_COMPUTE(c0, c1);
        c0 = n0; c1 = n1; t0 = tn;
    }
    CD_COMPUTE(c0, c1);
#undef CD_COMPUTE

    // Row epilogue: min over 32 cols via DPP (VALU) + 1 swizzle, direct store.
    // Row-in-tile = (e&3) + 8*(e>>2) + 4*g  (m74/m101 layout).
    float* __restrict__ outr = rowmin + (size_t)(dir * 4 + cg) * TOTAL;
#pragma unroll
    for (int e = 0; e < 16; ++e) {
        const float v0 = min32_dpp(r0[e]);
        const float v1 = min32_dpp(r1[e]);
        const int rl = (e & 3) + 8 * (e >> 2) + 4 * g;
        if (pidx == 0) {
            outr[rowbase +      rl] = fmaxf(v0, 0.0f);
            outr[rowbase + 32 + rl] = fmaxf(v1, 0.0f);
        }
    }
}

// Combine 4 colgroup slices per (dir,row), sum -> 128 block partials.
__global__ __launch_bounds__(256) void cd_combine(const float* __restrict__ rowmin,
                                                  float* __restrict__ partial) {
    __shared__ float sred[256];
    const int tid = blockIdx.x * 256 + threadIdx.x;   // [0, 32768)
    float s = 0.0f;
#pragma unroll
    for (int k = 0; k < 4; ++k) {
        const int i   = tid + k * 32768;              // [0, 131072)
        const int d   = i >> 16;                      // dir
        const int row = i & (TOTAL - 1);
        const float* base = rowmin + (size_t)d * 4 * TOTAL + row;
        s += fminf(fminf(base[0], base[TOTAL]),
                   fminf(base[2 * TOTAL], base[3 * TOTAL]));
    }
    sred[threadIdx.x] = s;
    __syncthreads();
    for (int st = 128; st > 0; st >>= 1) {
        if (threadIdx.x < st) sred[threadIdx.x] += sred[threadIdx.x + st];
        __syncthreads();
    }
    if (threadIdx.x == 0) partial[blockIdx.x] = sred[0];
}

__global__ __launch_bounds__(NPART) void cd_final(const float* __restrict__ partial,
                                                  float* __restrict__ out) {
    __shared__ float sred[NPART];
    sred[threadIdx.x] = partial[threadIdx.x];
    __syncthreads();
    for (int st = NPART / 2; st > 0; st >>= 1) {
        if (threadIdx.x < st) sred[threadIdx.x] += sred[threadIdx.x + st];
        __syncthreads();
    }
    if (threadIdx.x == 0) out[0] = sred[0] * (1.0f / (float)BQ);
}

// ---------------- fallback (ws too small): R2 LDS-scalar path ----------------
__global__ __launch_bounds__(256) void cd_init_ws(unsigned int* __restrict__ ws) {
    ws[blockIdx.x * 256 + threadIdx.x] = 0x7F800000u;
}
#define F_APT 8
__global__ __launch_bounds__(256) void cd_min_lds(
        const float* __restrict__ p1, const float* __restrict__ p2,
        unsigned int* __restrict__ wsmin) {
    const int dir = blockIdx.y;
    const float* __restrict__ Aset = dir ? p2 : p1;
    const float* __restrict__ Bset = dir ? p1 : p2;
    unsigned int* __restrict__ outmin = wsmin + dir * TOTAL;
    const int atile = blockIdx.x / 16;
    const int mtile = blockIdx.x % 16;
    const int a0 = atile * 2048;
    const int m0 = (a0 / NPTS) * NPTS + mtile * 256;
    __shared__ float4 sbf[256];
    {
        const float* bpn = Bset + (size_t)(m0 + threadIdx.x) * 3;
        float bx = bpn[0], by = bpn[1], bz = bpn[2];
        sbf[threadIdx.x] = make_float4(-2.0f*bx, -2.0f*by, -2.0f*bz,
                                       fmaf(bx,bx,fmaf(by,by,bz*bz)));
    }
    __syncthreads();
    float ax[F_APT], ay[F_APT], az_[F_APT], q2[F_APT], mn[F_APT];
#pragma unroll
    for (int k = 0; k < F_APT; ++k) {
        const int ai = a0 + k*256 + threadIdx.x;
        const float* ap = Aset + (size_t)ai * 3;
        ax[k]=ap[0]; ay[k]=ap[1]; az_[k]=ap[2];
        q2[k]=fmaf(ax[k],ax[k],fmaf(ay[k],ay[k],az_[k]*az_[k]));
        mn[k]=3.0e38f;
    }
#pragma unroll 2
    for (int j = 0; j < 256; j += 2) {
        const float4 b0 = sbf[j], b1 = sbf[j+1];
#pragma unroll
        for (int k = 0; k < F_APT; ++k) {
            float d0 = fmaf(az_[k],b0.z,b0.w); d0=fmaf(ay[k],b0.y,d0); d0=fmaf(ax[k],b0.x,d0);
            float d1 = fmaf(az_[k],b1.z,b1.w); d1=fmaf(ay[k],b1.y,d1); d1=fmaf(ax[k],b1.x,d1);
            mn[k] = fminf(fminf(mn[k], d0), d1);
        }
    }
#pragma unroll
    for (int k = 0; k < F_APT; ++k) {
        const int ai = a0 + k*256 + threadIdx.x;
        atomicMin(&outmin[ai], __float_as_uint(fmaxf(q2[k]+mn[k], 0.0f)));
    }
}
__global__ __launch_bounds__(1024) void cd_reduce_single(const float* __restrict__ wsmin,
                                                         float* __restrict__ out) {
    __shared__ float sred[1024];
    const float4* __restrict__ v = (const float4*)wsmin;
    float s = 0.0f;
    for (int i = threadIdx.x; i < (2*TOTAL)/4; i += 1024) {
        float4 x = v[i]; s += (x.x + x.y) + (x.z + x.w);
    }
    sred[threadIdx.x] = s;
    __syncthreads();
    for (int st = 512; st > 0; st >>= 1) {
        if (threadIdx.x < st) sred[threadIdx.x] += sred[threadIdx.x + st];
        __syncthreads();
    }
    if (threadIdx.x == 0) out[0] = sred[0] * (1.0f / (float)BQ);
}

extern "C" void kernel_launch(void* const* d_in, const int* in_sizes, int n_in,
                              void* d_out, int out_size, void* d_ws, size_t ws_size,
                              hipStream_t stream) {
    const float* p1 = (const float*)d_in[0];
    const float* p2 = (const float*)d_in[1];
    float* out = (float*)d_out;

    if (ws_size >= WS_NEED) {
        float* rowmin  = (float*)d_ws;                      // 2 MiB
        float* partial = (float*)((char*)d_ws + ROWMIN_FLOATS * 4);

        dim3 grid(1024, 2, 1);
        cd_main<<<grid, 256, 0, stream>>>(p1, p2, rowmin);
        cd_combine<<<128, 256, 0, stream>>>(rowmin, partial);
        cd_final<<<1, NPART, 0, stream>>>(partial, out);
    } else {
        unsigned* wsmin = (unsigned*)d_ws;                  // 512 KiB
        cd_init_ws<<<(2 * TOTAL) / 256, 256, 0, stream>>>(wsmin);
        dim3 grid(512, 2, 1);
        cd_min_lds<<<grid, 256, 0, stream>>>(p1, p2, wsmin);
        cd_reduce_single<<<1, 1024, 0, stream>>>((const float*)wsmin, out);
    }
}